// Round 7
// baseline (217.361 us; speedup 1.0000x reference)
//
#include <hip/hip_runtime.h>
#include <hip/hip_bf16.h>
#include <stdint.h>

#define D_MODEL 1024
#define NH 16
#define DK 64
#define S_LEN 2048

typedef __attribute__((ext_vector_type(8))) __bf16 bf16x8;
typedef __attribute__((ext_vector_type(4))) float f32x4;

#define GLOBAL_AS __attribute__((address_space(1)))
#define LDS_AS    __attribute__((address_space(3)))

// async global->LDS DMA, 16B per lane; lane i's 16B lands at ldsbase + i*16.
__device__ __forceinline__ void async16(const ushort* g, ushort* l) {
    __builtin_amdgcn_global_load_lds(
        (const GLOBAL_AS uint32_t*)(uintptr_t)(const void*)g,
        (LDS_AS uint32_t*)(uint32_t)(uintptr_t)(void*)l,
        16, 0, 0);
}

// raw barrier with fine-grained vmcnt: waits until <=N VMEM ops outstanding.
template <int N>
__device__ __forceinline__ void pipe_barrier() {
    asm volatile("s_waitcnt vmcnt(%0)\n\ts_barrier" :: "n"(N) : "memory");
}

__device__ __forceinline__ float fast_exp2(float x) {
    float r;
    asm("v_exp_f32 %0, %1" : "=v"(r) : "v"(x));   // D = 2^S0
    return r;
}

// fp32 -> bf16 (RNE)
__device__ __forceinline__ ushort f2bf(float f) {
    union { float f; uint32_t u; } v; v.f = f;
    uint32_t lsb = (v.u >> 16) & 1u;
    return (ushort)((v.u + 0x7fffu + lsb) >> 16);
}

// two fp32 -> packed bf16x2 (round-half-up)
__device__ __forceinline__ uint32_t packbf(float a, float b) {
    union { float f; uint32_t u; } x, y; x.f = a; y.f = b;
    return ((x.u + 0x8000u) >> 16) | ((y.u + 0x8000u) & 0xffff0000u);
}

__device__ __forceinline__ bf16x8 ldfrag(const ushort* p) {
    union { uint4 u; bf16x8 b; } cv;
    cv.u = *(const uint4*)p;
    return cv.b;
}

// ---------------- convert kernels ----------------

__global__ void cvt_x_kernel(const float* __restrict__ x, ushort* __restrict__ xb) {
    int i = blockIdx.x * 256 + threadIdx.x;
    float4 v = ((const float4*)x)[i];
    ushort4 o;
    o.x = f2bf(v.x); o.y = f2bf(v.y); o.z = f2bf(v.z); o.w = f2bf(v.w);
    ((ushort4*)xb)[i] = o;
}

__global__ void transpose_cvt4_kernel(
    const float* __restrict__ W0, const float* __restrict__ W1,
    const float* __restrict__ W2, const float* __restrict__ W3,
    ushort* __restrict__ D0, ushort* __restrict__ D1,
    ushort* __restrict__ D2, ushort* __restrict__ D3) {
    const float* W; ushort* D;
    switch (blockIdx.z) {
        case 0: W = W0; D = D0; break;
        case 1: W = W1; D = D1; break;
        case 2: W = W2; D = D2; break;
        default: W = W3; D = D3; break;
    }
    __shared__ float tile[32][33];
    int bx = blockIdx.x * 32, by = blockIdx.y * 32;
    int tx = threadIdx.x, ty = threadIdx.y;
#pragma unroll
    for (int j = 0; j < 32; j += 8)
        tile[ty + j][tx] = W[(size_t)(by + ty + j) * D_MODEL + bx + tx];
    __syncthreads();
#pragma unroll
    for (int j = 0; j < 32; j += 8)
        D[(size_t)(bx + ty + j) * D_MODEL + by + tx] = f2bf(tile[tx][ty + j]);
}

__global__ void cvt_bias_kernel(const float* __restrict__ bq, const float* __restrict__ bk,
                                const float* __restrict__ bv, float* __restrict__ out) {
    int i = blockIdx.x * 256 + threadIdx.x;  // 3072
    float v = (i < 1024) ? bq[i] : (i < 2048 ? bk[i - 1024] : bv[i - 2048]);
    out[i] = v;
}

// ---------------- MFMA GEMM (unchanged from R6) -------------------------------
template <int MODE>
__global__ __launch_bounds__(256) void gemm_kernel(
    const ushort* __restrict__ A, const ushort* __restrict__ Bt,
    const float* __restrict__ bias,
    ushort* __restrict__ outQ, ushort* __restrict__ outK, ushort* __restrict__ outVt,
    const float* __restrict__ xres, float* __restrict__ outF) {
    constexpr int BN = (MODE == 0) ? 128 : 64;
    constexpr int NI = (MODE == 0) ? 4 : 2;
    constexpr int NS = (MODE == 0) ? 4 : 3;
    constexpr int ABUF = 4096;
    constexpr int BBUF = (MODE == 0) ? 4096 : 2048;
    constexpr int SMEM = (MODE == 0) ? 32768 : 24576;
    __shared__ __align__(16) ushort smem[SMEM];
    ushort* sAb = smem;
    ushort* sBb = smem + 4 * ABUF;

    const int tid = threadIdx.x;
    const int wave = tid >> 6, lane = tid & 63;
    const int lr = lane & 15, lq = lane >> 4;
    const int srow = lane >> 3, sp = lane & 7;

    const int bid = blockIdx.x;
    const int xcd = bid & 7, lb = bid >> 3;
    int bx, by;
    if (MODE == 0) { bx = xcd * 3 + (lb % 3); by = lb / 3; }
    else           { by = xcd * 4 + (lb & 3); bx = lb >> 2; }
    const int blockM = by * 128;
    const int blockN = bx * BN;
    const int waveM = (wave >> 1) * 64;
    const int waveN = (MODE == 0) ? (wave & 1) * 64 : (wave & 1) * 32;

    auto stage = [&](int k0, int buf) {
        ushort* a = sAb + buf * ABUF;
#pragma unroll
        for (int t = 0; t < 2; t++) {
            int Rb = wave * 16 + t * 8;
            int R = Rb + srow;
            int L = sp ^ (R & 7);
            int m = 2 * R + (L >> 2);
            int kc = L & 3;
            async16(&A[(size_t)(blockM + m) * D_MODEL + k0 + kc * 8], a + Rb * 64);
        }
        ushort* b = sBb + buf * BBUF;
        if (MODE == 0) {
#pragma unroll
            for (int t = 0; t < 2; t++) {
                int Rb = wave * 16 + t * 8;
                int R = Rb + srow;
                int L = sp ^ (R & 7);
                int n = 2 * R + (L >> 2);
                int kc = L & 3;
                async16(&Bt[(size_t)(blockN + n) * D_MODEL + k0 + kc * 8], b + Rb * 64);
            }
        } else {
            int Rb = wave * 8;
            int R = Rb + srow;
            int L = sp ^ (R & 7);
            int n = 2 * R + (L >> 2);
            int kc = L & 3;
            async16(&Bt[(size_t)(blockN + n) * D_MODEL + k0 + kc * 8], b + Rb * 64);
        }
    };

    const int RA = (waveM >> 1) + (lr >> 1);
    const int offA = RA * 64 + ((((lr & 1) * 4 + lq) ^ (RA & 7)) * 8);
    const int RB = (waveN >> 1) + (lr >> 1);
    const int offB = RB * 64 + ((((lr & 1) * 4 + lq) ^ (RB & 7)) * 8);

    f32x4 acc[4][NI] = {};

    stage(0, 0);
    stage(32, 1);
    stage(64, 2);
    pipe_barrier<2 * NS>();

#pragma unroll 4
    for (int k = 0; k < 32; k++) {
        const int buf = k & 3;
        if (k + 3 < 32) stage((k + 3) * 32, (k + 3) & 3);
        const ushort* a = sAb + buf * ABUF;
        const ushort* b = sBb + buf * BBUF;
        bf16x8 af[4], bfr[NI];
#pragma unroll
        for (int mi = 0; mi < 4; mi++)
            af[mi] = ldfrag(&a[offA + mi * 512]);
#pragma unroll
        for (int ni = 0; ni < NI; ni++)
            bfr[ni] = ldfrag(&b[offB + ni * 512]);
#pragma unroll
        for (int mi = 0; mi < 4; mi++)
#pragma unroll
            for (int ni = 0; ni < NI; ni++)
                acc[mi][ni] = __builtin_amdgcn_mfma_f32_16x16x32_bf16(
                    af[mi], bfr[ni], acc[mi][ni], 0, 0, 0);
        if (k < 30) pipe_barrier<2 * NS>();
        else if (k == 30) pipe_barrier<0>();
    }
    __syncthreads();

    const int bglob = blockM >> 11;
    const int sbase = blockM & 2047;

    if (MODE == 0) {
        const int which = bx >> 3;
        if (which < 2) {
            const float scale = (which == 0) ? 0.1803368801f : 1.0f;
#pragma unroll
            for (int ni = 0; ni < 4; ni++) {
                const int n_loc = waveN + ni * 16 + lr;
                const float bn = bias[blockN + n_loc];
#pragma unroll
                for (int mi = 0; mi < 4; mi++)
#pragma unroll
                    for (int r = 0; r < 4; r++) {
                        int m_loc = waveM + mi * 16 + lq * 4 + r;
                        smem[m_loc * 136 + n_loc] =
                            f2bf((acc[mi][ni][r] + bn) * scale);
                    }
            }
            __syncthreads();
            ushort* outp = (which == 0) ? outQ : outK;
            const int hbase = (which == 0) ? bx * 2 : (bx - 8) * 2;
#pragma unroll
            for (int j = 0; j < 8; j++) {
                int c = tid + j * 256;
                int m = c >> 4, nc = c & 15;
                int hh = nc >> 3, d8 = nc & 7;
                uint4 w = *(uint4*)&smem[m * 136 + nc * 8];
                size_t bh = (size_t)(bglob * NH + hbase + hh);
                *(uint4*)&outp[(bh * S_LEN + sbase + m) * DK + d8 * 8] = w;
            }
        } else {
#pragma unroll
            for (int ni = 0; ni < 4; ni++) {
                const int n_loc = waveN + ni * 16 + lr;
                const float bn = bias[blockN + n_loc];
#pragma unroll
                for (int mi = 0; mi < 4; mi++) {
                    uint2 w;
                    w.x = packbf(acc[mi][ni][0] + bn, acc[mi][ni][1] + bn);
                    w.y = packbf(acc[mi][ni][2] + bn, acc[mi][ni][3] + bn);
                    int m_base = waveM + mi * 16 + lq * 4;
                    *(uint2*)&smem[n_loc * 136 + m_base] = w;
                }
            }
            __syncthreads();
            const int hbase = (bx - 16) * 2;
#pragma unroll
            for (int j = 0; j < 8; j++) {
                int c = tid + j * 256;
                int n_loc = c >> 4, m8 = c & 15;
                int d = n_loc & 63, hh = n_loc >> 6;
                uint4 w = *(uint4*)&smem[n_loc * 136 + m8 * 8];
                size_t bh = (size_t)(bglob * NH + hbase + hh);
                *(uint4*)&outVt[(bh * DK + d) * S_LEN + sbase + m8 * 8] = w;
            }
        }
    } else {
        float* sCf = (float*)smem;
#pragma unroll
        for (int ni = 0; ni < 2; ni++) {
            const int n_loc = waveN + ni * 16 + lr;
            const float bn = bias[blockN + n_loc];
#pragma unroll
            for (int mi = 0; mi < 4; mi++)
#pragma unroll
                for (int r = 0; r < 4; r++) {
                    int m_loc = waveM + mi * 16 + lq * 4 + r;
                    sCf[m_loc * 68 + n_loc] = acc[mi][ni][r] + bn;
                }
        }
        __syncthreads();
#pragma unroll
        for (int j = 0; j < 8; j++) {
            int c = tid + j * 256;
            int m = c >> 4, nc = c & 15;
            float4 v = *(float4*)&sCf[m * 68 + nc * 4];
            size_t idx = (size_t)(blockM + m) * D_MODEL + blockN + nc * 4;
            float4 xr = *(const float4*)&xres[idx];
            v.x += xr.x; v.y += xr.y; v.z += xr.z; v.w += xr.w;
            *(float4*)&outF[idx] = v;
        }
    }
}

// ---------------- flash attention: q=64/wave ----------------------------------
// block 256 (4 waves), q-tile 256, grid 256 (1 block/CU). Per-CU LDS traffic
// halves vs q=32 (4 waves instead of 8 re-read the shared K/V tiles) -> MFMA
// becomes the binding resource. Double-buffered K/V; per-wave Q region is
// aliased by P after Q fragments are hoisted to registers. Row-sums in VALU.
__global__ __launch_bounds__(256, 1) void attn_kernel(
    const ushort* __restrict__ Q, const ushort* __restrict__ Km,
    const ushort* __restrict__ Vt, ushort* __restrict__ ctx) {
    const int bid = blockIdx.x;
    const int xcd = bid & 7, lb = bid >> 3;       // lb 0..31 per XCD
    const int bh = xcd * 4 + (lb & 3);
    const int qt = lb >> 2;                       // 8 q-tiles of 256
    const int q0 = qt * 256;
    __shared__ __align__(16) ushort sK[2][64 * 64];   // [kpos][d] swizzled, 16 KB
    __shared__ __align__(16) ushort sV[2][64 * 64];   // [d][kpos] swizzled, 16 KB
    __shared__ __align__(16) ushort sQP[4][64 * 64];  // per-wave Q then P, 32 KB
    const int tid = threadIdx.x;
    const int wave = tid >> 6, lane = tid & 63;
    const int lr = lane & 15, lq = lane >> 4;
    const int srow = lane >> 3, sp = lane & 7;        // 128B-row staging
    const ushort* Qh = Q + (size_t)bh * S_LEN * DK;
    const ushort* Kh = Km + (size_t)bh * S_LEN * DK;
    const ushort* Vh = Vt + (size_t)bh * DK * S_LEN;
    ushort* sPw = sQP[wave];

    // stage this wave's 64 Q rows into its own (future-P) region
#pragma unroll
    for (int t = 0; t < 8; t++) {
        int row = t * 8 + srow;                       // local 0..63
        int c = sp ^ (row & 7);
        async16(&Qh[(size_t)(q0 + wave * 64 + row) * DK + c * 8],
                &sPw[t * 8 * 64]);
    }

    auto stageKV = [&](int k0, int buf) {
#pragma unroll
        for (int t = 0; t < 2; t++) {
            int row = wave * 16 + t * 8 + srow;
            int c = sp ^ (row & 7);
            async16(&Kh[(size_t)(k0 + row) * DK + c * 8],
                    &sK[buf][(wave * 16 + t * 8) * 64]);
            async16(&Vh[(size_t)row * S_LEN + k0 + c * 8],
                    &sV[buf][(wave * 16 + t * 8) * 64]);
        }
    };

    stageKV(0, 0);
    __syncthreads();   // drains Q + buf0

    // hoist Q fragments to registers (B-operand for S^T): q = wave*64+nj*16+lr
    bf16x8 qf[4][2];
#pragma unroll
    for (int nj = 0; nj < 4; nj++)
#pragma unroll
        for (int kk = 0; kk < 2; kk++)
            qf[nj][kk] = ldfrag(&sPw[(nj * 16 + lr) * 64 +
                                     (((kk * 4 + lq) ^ (lr & 7)) * 8)]);

    f32x4 cacc[4][4] = {};
    float lsum[4] = {0.f, 0.f, 0.f, 0.f};

    for (int k = 0; k < 32; k++) {
        const int buf = k & 1;
        if (k + 1 < 32) stageKV((k + 1) * 64, buf ^ 1);
        const ushort* sk = sK[buf];
        const ushort* sv = sV[buf];

        // S^T = K . Q^T : 64 kpos rows (4 mi), 64 q cols (4 nj)
        f32x4 sacc[4][4] = {};
#pragma unroll
        for (int kk = 0; kk < 2; kk++) {
            bf16x8 kf[4];
            int swz = ((kk * 4 + lq) ^ (lr & 7)) * 8;
#pragma unroll
            for (int mi = 0; mi < 4; mi++)
                kf[mi] = ldfrag(&sk[(mi * 16 + lr) * 64 + swz]);
#pragma unroll
            for (int mi = 0; mi < 4; mi++)
#pragma unroll
                for (int nj = 0; nj < 4; nj++)
                    sacc[mi][nj] = __builtin_amdgcn_mfma_f32_16x16x32_bf16(
                        kf[mi], qf[nj][kk], sacc[mi][nj], 0, 0, 0);
        }

        // P = exp2(S^T) -> packed bf16 into the per-wave region; VALU row-sums.
        // lane holds q = nj*16+lr, kpos = mi*16 + lq*4 + r.
#pragma unroll
        for (int mi = 0; mi < 4; mi++)
#pragma unroll
            for (int nj = 0; nj < 4; nj++) {
                float p0 = fast_exp2(sacc[mi][nj][0]);
                float p1 = fast_exp2(sacc[mi][nj][1]);
                float p2 = fast_exp2(sacc[mi][nj][2]);
                float p3 = fast_exp2(sacc[mi][nj][3]);
                lsum[nj] += (p0 + p1) + (p2 + p3);
                uint2 w;
                w.x = packbf(p0, p1);
                w.y = packbf(p2, p3);
                int physc = (mi * 2 + (lq >> 1)) ^ (lr & 7);
                *(uint2*)&sPw[(nj * 16 + lr) * 64 + physc * 8 + (lq & 1) * 4] = w;
            }

        // ctx += P.V (same-wave LDS ordering: no barrier needed)
#pragma unroll
        for (int ks = 0; ks < 2; ks++) {
            bf16x8 pf[4], vf[4];
            int swz = ((ks * 4 + lq) ^ (lr & 7)) * 8;
#pragma unroll
            for (int nj = 0; nj < 4; nj++)
                pf[nj] = ldfrag(&sPw[(nj * 16 + lr) * 64 + swz]);
#pragma unroll
            for (int nd = 0; nd < 4; nd++)
                vf[nd] = ldfrag(&sv[(nd * 16 + lr) * 64 + swz]);
#pragma unroll
            for (int nj = 0; nj < 4; nj++)
#pragma unroll
                for (int nd = 0; nd < 4; nd++)
                    cacc[nj][nd] = __builtin_amdgcn_mfma_f32_16x16x32_bf16(
                        pf[nj], vf[nd], cacc[nj][nd], 0, 0, 0);
        }

        // next tile's DMAs were issued a full compute phase ago -> cheap drain
        if (k < 31) pipe_barrier<0>();
    }

    // row-sums: lane's lsum covers its lq-slice of kpos; reduce across lq
    float inv[4];
#pragma unroll
    for (int nj = 0; nj < 4; nj++) {
        float l = lsum[nj];
        l += __shfl_xor(l, 16);
        l += __shfl_xor(l, 32);
        inv[nj] = __builtin_amdgcn_rcpf(l);       // valid for q = nj*16 + lr
    }
    float invr[4][4];
#pragma unroll
    for (int nj = 0; nj < 4; nj++)
#pragma unroll
        for (int r = 0; r < 4; r++)
            invr[nj][r] = __shfl(inv[nj], lq * 4 + r);

    const int b = bh >> 4, h = bh & 15;
#pragma unroll
    for (int nj = 0; nj < 4; nj++)
#pragma unroll
        for (int nd = 0; nd < 4; nd++)
#pragma unroll
            for (int r = 0; r < 4; r++) {
                int qrow = q0 + wave * 64 + nj * 16 + lq * 4 + r;
                int d = nd * 16 + lr;
                float v = cacc[nj][nd][r] * invr[nj][r];
                ctx[(size_t)(b * S_LEN + qrow) * D_MODEL + h * DK + d] = f2bf(v);
            }
}

// ---------------- launch ----------------

extern "C" void kernel_launch(void* const* d_in, const int* in_sizes, int n_in,
                              void* d_out, int out_size, void* d_ws, size_t ws_size,
                              hipStream_t stream) {
    const float* x  = (const float*)d_in[0];
    const float* Wq = (const float*)d_in[1];
    const float* bq = (const float*)d_in[2];
    const float* Wk = (const float*)d_in[3];
    const float* bk = (const float*)d_in[4];
    const float* Wv = (const float*)d_in[5];
    const float* bv = (const float*)d_in[6];
    const float* Wo = (const float*)d_in[7];
    const float* bo = (const float*)d_in[8];

    char* ws = (char*)d_ws;
    ushort* xb    = (ushort*)(ws);                        // 8 MB
    ushort* wqkv  = (ushort*)(ws + (8ull  << 20));        // 6 MB (B^T)
    ushort* wo_t  = (ushort*)(ws + (14ull << 20));        // 2 MB (B^T)
    ushort* qbuf  = (ushort*)(ws + (16ull << 20));        // 8 MB [32][2048][64]
    ushort* kbuf  = (ushort*)(ws + (24ull << 20));        // 8 MB [32][2048][64]
    ushort* vtb   = (ushort*)(ws + (32ull << 20));        // 8 MB [32][64][2048]
    ushort* ctx   = (ushort*)(ws + (40ull << 20));        // 8 MB [4096][1024]
    float*  biasq = (float*)(ws + (48ull << 20));         // 12 KB [3072]

    cvt_x_kernel<<<4096, 256, 0, stream>>>(x, xb);
    transpose_cvt4_kernel<<<dim3(32, 32, 4), dim3(32, 8), 0, stream>>>(
        Wq, Wk, Wv, Wo, wqkv, wqkv + 1024 * 1024, wqkv + 2 * 1024 * 1024, wo_t);
    cvt_bias_kernel<<<12, 256, 0, stream>>>(bq, bk, bv, biasq);

    gemm_kernel<0><<<768, 256, 0, stream>>>(
        xb, wqkv, biasq, qbuf, kbuf, vtb, nullptr, nullptr);
    attn_kernel<<<256, 256, 0, stream>>>(qbuf, kbuf, vtb, ctx);
    gemm_kernel<1><<<512, 256, 0, stream>>>(
        ctx, wo_t, bo, nullptr, nullptr, nullptr, x, (float*)d_out);
}

// Round 8
// 214.911 us; speedup vs baseline: 1.0114x; 1.0114x over previous
//
#include <hip/hip_runtime.h>
#include <hip/hip_bf16.h>
#include <stdint.h>

#define D_MODEL 1024
#define NH 16
#define DK 64
#define S_LEN 2048

typedef __attribute__((ext_vector_type(8))) __bf16 bf16x8;
typedef __attribute__((ext_vector_type(4))) float f32x4;

#define GLOBAL_AS __attribute__((address_space(1)))
#define LDS_AS    __attribute__((address_space(3)))

// async global->LDS DMA, 16B per lane; lane i's 16B lands at ldsbase + i*16.
__device__ __forceinline__ void async16(const ushort* g, ushort* l) {
    __builtin_amdgcn_global_load_lds(
        (const GLOBAL_AS uint32_t*)(uintptr_t)(const void*)g,
        (LDS_AS uint32_t*)(uint32_t)(uintptr_t)(void*)l,
        16, 0, 0);
}

// barrier + fine-grained vmcnt (for the GEMM pipeline)
template <int N>
__device__ __forceinline__ void pipe_barrier() {
    asm volatile("s_waitcnt vmcnt(%0)\n\ts_barrier" :: "n"(N) : "memory");
}

// wave-local wait: no barrier (attention's per-wave pipeline)
template <int N>
__device__ __forceinline__ void pipe_wait() {
    asm volatile("s_waitcnt vmcnt(%0)" :: "n"(N) : "memory");
}

__device__ __forceinline__ float fast_exp2(float x) {
    float r;
    asm("v_exp_f32 %0, %1" : "=v"(r) : "v"(x));   // D = 2^S0
    return r;
}

// fp32 -> bf16 (RNE)
__device__ __forceinline__ ushort f2bf(float f) {
    union { float f; uint32_t u; } v; v.f = f;
    uint32_t lsb = (v.u >> 16) & 1u;
    return (ushort)((v.u + 0x7fffu + lsb) >> 16);
}

// two fp32 -> packed bf16x2 (round-half-up)
__device__ __forceinline__ uint32_t packbf(float a, float b) {
    union { float f; uint32_t u; } x, y; x.f = a; y.f = b;
    return ((x.u + 0x8000u) >> 16) | ((y.u + 0x8000u) & 0xffff0000u);
}

__device__ __forceinline__ bf16x8 ldfrag(const ushort* p) {
    union { uint4 u; bf16x8 b; } cv;
    cv.u = *(const uint4*)p;
    return cv.b;
}

__device__ __forceinline__ bf16x8 ldfrag2(const ushort* p0, const ushort* p1) {
    union { uint4 u; bf16x8 b; } cv;
    uint2 a = *(const uint2*)p0;
    uint2 b2 = *(const uint2*)p1;
    cv.u = make_uint4(a.x, a.y, b2.x, b2.y);
    return cv.b;
}

// ---------------- convert kernels ----------------

__global__ void cvt_x_kernel(const float* __restrict__ x, ushort* __restrict__ xb) {
    int i = blockIdx.x * 256 + threadIdx.x;
    float4 v = ((const float4*)x)[i];
    ushort4 o;
    o.x = f2bf(v.x); o.y = f2bf(v.y); o.z = f2bf(v.z); o.w = f2bf(v.w);
    ((ushort4*)xb)[i] = o;
}

__global__ void transpose_cvt4_kernel(
    const float* __restrict__ W0, const float* __restrict__ W1,
    const float* __restrict__ W2, const float* __restrict__ W3,
    ushort* __restrict__ D0, ushort* __restrict__ D1,
    ushort* __restrict__ D2, ushort* __restrict__ D3) {
    const float* W; ushort* D;
    switch (blockIdx.z) {
        case 0: W = W0; D = D0; break;
        case 1: W = W1; D = D1; break;
        case 2: W = W2; D = D2; break;
        default: W = W3; D = D3; break;
    }
    __shared__ float tile[32][33];
    int bx = blockIdx.x * 32, by = blockIdx.y * 32;
    int tx = threadIdx.x, ty = threadIdx.y;
#pragma unroll
    for (int j = 0; j < 32; j += 8)
        tile[ty + j][tx] = W[(size_t)(by + ty + j) * D_MODEL + bx + tx];
    __syncthreads();
#pragma unroll
    for (int j = 0; j < 32; j += 8)
        D[(size_t)(bx + ty + j) * D_MODEL + by + tx] = f2bf(tile[tx][ty + j]);
}

__global__ void cvt_bias_kernel(const float* __restrict__ bq, const float* __restrict__ bk,
                                const float* __restrict__ bv, float* __restrict__ out) {
    int i = blockIdx.x * 256 + threadIdx.x;  // 3072
    float v = (i < 1024) ? bq[i] : (i < 2048 ? bk[i - 1024] : bv[i - 2048]);
    out[i] = v;
}

// ---------------- MFMA GEMM (unchanged from R6) -------------------------------
template <int MODE>
__global__ __launch_bounds__(256) void gemm_kernel(
    const ushort* __restrict__ A, const ushort* __restrict__ Bt,
    const float* __restrict__ bias,
    ushort* __restrict__ outQ, ushort* __restrict__ outK, ushort* __restrict__ outVt,
    const float* __restrict__ xres, float* __restrict__ outF) {
    constexpr int BN = (MODE == 0) ? 128 : 64;
    constexpr int NI = (MODE == 0) ? 4 : 2;
    constexpr int NS = (MODE == 0) ? 4 : 3;
    constexpr int ABUF = 4096;
    constexpr int BBUF = (MODE == 0) ? 4096 : 2048;
    constexpr int SMEM = (MODE == 0) ? 32768 : 24576;
    __shared__ __align__(16) ushort smem[SMEM];
    ushort* sAb = smem;
    ushort* sBb = smem + 4 * ABUF;

    const int tid = threadIdx.x;
    const int wave = tid >> 6, lane = tid & 63;
    const int lr = lane & 15, lq = lane >> 4;
    const int srow = lane >> 3, sp = lane & 7;

    const int bid = blockIdx.x;
    const int xcd = bid & 7, lb = bid >> 3;
    int bx, by;
    if (MODE == 0) { bx = xcd * 3 + (lb % 3); by = lb / 3; }
    else           { by = xcd * 4 + (lb & 3); bx = lb >> 2; }
    const int blockM = by * 128;
    const int blockN = bx * BN;
    const int waveM = (wave >> 1) * 64;
    const int waveN = (MODE == 0) ? (wave & 1) * 64 : (wave & 1) * 32;

    auto stage = [&](int k0, int buf) {
        ushort* a = sAb + buf * ABUF;
#pragma unroll
        for (int t = 0; t < 2; t++) {
            int Rb = wave * 16 + t * 8;
            int R = Rb + srow;
            int L = sp ^ (R & 7);
            int m = 2 * R + (L >> 2);
            int kc = L & 3;
            async16(&A[(size_t)(blockM + m) * D_MODEL + k0 + kc * 8], a + Rb * 64);
        }
        ushort* b = sBb + buf * BBUF;
        if (MODE == 0) {
#pragma unroll
            for (int t = 0; t < 2; t++) {
                int Rb = wave * 16 + t * 8;
                int R = Rb + srow;
                int L = sp ^ (R & 7);
                int n = 2 * R + (L >> 2);
                int kc = L & 3;
                async16(&Bt[(size_t)(blockN + n) * D_MODEL + k0 + kc * 8], b + Rb * 64);
            }
        } else {
            int Rb = wave * 8;
            int R = Rb + srow;
            int L = sp ^ (R & 7);
            int n = 2 * R + (L >> 2);
            int kc = L & 3;
            async16(&Bt[(size_t)(blockN + n) * D_MODEL + k0 + kc * 8], b + Rb * 64);
        }
    };

    const int RA = (waveM >> 1) + (lr >> 1);
    const int offA = RA * 64 + ((((lr & 1) * 4 + lq) ^ (RA & 7)) * 8);
    const int RB = (waveN >> 1) + (lr >> 1);
    const int offB = RB * 64 + ((((lr & 1) * 4 + lq) ^ (RB & 7)) * 8);

    f32x4 acc[4][NI] = {};

    stage(0, 0);
    stage(32, 1);
    stage(64, 2);
    pipe_barrier<2 * NS>();

#pragma unroll 4
    for (int k = 0; k < 32; k++) {
        const int buf = k & 3;
        if (k + 3 < 32) stage((k + 3) * 32, (k + 3) & 3);
        const ushort* a = sAb + buf * ABUF;
        const ushort* b = sBb + buf * BBUF;
        bf16x8 af[4], bfr[NI];
#pragma unroll
        for (int mi = 0; mi < 4; mi++)
            af[mi] = ldfrag(&a[offA + mi * 512]);
#pragma unroll
        for (int ni = 0; ni < NI; ni++)
            bfr[ni] = ldfrag(&b[offB + ni * 512]);
#pragma unroll
        for (int mi = 0; mi < 4; mi++)
#pragma unroll
            for (int ni = 0; ni < NI; ni++)
                acc[mi][ni] = __builtin_amdgcn_mfma_f32_16x16x32_bf16(
                    af[mi], bfr[ni], acc[mi][ni], 0, 0, 0);
        if (k < 30) pipe_barrier<2 * NS>();
        else if (k == 30) pipe_barrier<0>();
    }
    __syncthreads();

    const int bglob = blockM >> 11;
    const int sbase = blockM & 2047;

    if (MODE == 0) {
        const int which = bx >> 3;
        if (which < 2) {
            const float scale = (which == 0) ? 0.1803368801f : 1.0f;
#pragma unroll
            for (int ni = 0; ni < 4; ni++) {
                const int n_loc = waveN + ni * 16 + lr;
                const float bn = bias[blockN + n_loc];
#pragma unroll
                for (int mi = 0; mi < 4; mi++)
#pragma unroll
                    for (int r = 0; r < 4; r++) {
                        int m_loc = waveM + mi * 16 + lq * 4 + r;
                        smem[m_loc * 136 + n_loc] =
                            f2bf((acc[mi][ni][r] + bn) * scale);
                    }
            }
            __syncthreads();
            ushort* outp = (which == 0) ? outQ : outK;
            const int hbase = (which == 0) ? bx * 2 : (bx - 8) * 2;
#pragma unroll
            for (int j = 0; j < 8; j++) {
                int c = tid + j * 256;
                int m = c >> 4, nc = c & 15;
                int hh = nc >> 3, d8 = nc & 7;
                uint4 w = *(uint4*)&smem[m * 136 + nc * 8];
                size_t bh = (size_t)(bglob * NH + hbase + hh);
                *(uint4*)&outp[(bh * S_LEN + sbase + m) * DK + d8 * 8] = w;
            }
        } else {
#pragma unroll
            for (int ni = 0; ni < 4; ni++) {
                const int n_loc = waveN + ni * 16 + lr;
                const float bn = bias[blockN + n_loc];
#pragma unroll
                for (int mi = 0; mi < 4; mi++) {
                    uint2 w;
                    w.x = packbf(acc[mi][ni][0] + bn, acc[mi][ni][1] + bn);
                    w.y = packbf(acc[mi][ni][2] + bn, acc[mi][ni][3] + bn);
                    int m_base = waveM + mi * 16 + lq * 4;
                    *(uint2*)&smem[n_loc * 136 + m_base] = w;
                }
            }
            __syncthreads();
            const int hbase = (bx - 16) * 2;
#pragma unroll
            for (int j = 0; j < 8; j++) {
                int c = tid + j * 256;
                int n_loc = c >> 4, m8 = c & 15;
                int d = n_loc & 63, hh = n_loc >> 6;
                uint4 w = *(uint4*)&smem[n_loc * 136 + m8 * 8];
                size_t bh = (size_t)(bglob * NH + hbase + hh);
                *(uint4*)&outVt[(bh * DK + d) * S_LEN + sbase + m8 * 8] = w;
            }
        }
    } else {
        float* sCf = (float*)smem;
#pragma unroll
        for (int ni = 0; ni < 2; ni++) {
            const int n_loc = waveN + ni * 16 + lr;
            const float bn = bias[blockN + n_loc];
#pragma unroll
            for (int mi = 0; mi < 4; mi++)
#pragma unroll
                for (int r = 0; r < 4; r++) {
                    int m_loc = waveM + mi * 16 + lq * 4 + r;
                    sCf[m_loc * 68 + n_loc] = acc[mi][ni][r] + bn;
                }
        }
        __syncthreads();
#pragma unroll
        for (int j = 0; j < 8; j++) {
            int c = tid + j * 256;
            int m = c >> 4, nc = c & 15;
            float4 v = *(float4*)&sCf[m * 68 + nc * 4];
            size_t idx = (size_t)(blockM + m) * D_MODEL + blockN + nc * 4;
            float4 xr = *(const float4*)&xres[idx];
            v.x += xr.x; v.y += xr.y; v.z += xr.z; v.w += xr.w;
            *(float4*)&outF[idx] = v;
        }
    }
}

// ---------------- flash attention: kpos-split, barrier-free K-loop ------------
// q-tile 64 shared by 4 waves; per 128-kpos tile, wave w owns kpos slice
// [w*32, w*32+32): stages and reads ONLY its own K/V slice and its private P
// -> every LDS byte read exactly once, no __syncthreads in the K-loop.
// Per-wave pipeline: K double-buffered (depth 2), V single-buffered; FIFO
// vmcnt(4) retires V(k)+K(k) while K(k+1) stays in flight. Cross-wave ctx
// reduction once at the end (tree: 1,3 write; 0,2 add; all finalize).
__global__ __launch_bounds__(256, 2) void attn_kernel(
    const ushort* __restrict__ Q, const ushort* __restrict__ Km,
    const ushort* __restrict__ Vt, ushort* __restrict__ ctx) {
    const int bid = blockIdx.x;
    const int xcd = bid & 7, lb = bid >> 3;   // lb 0..127
    const int bh = xcd * 4 + (lb & 3);
    const int qt = lb >> 2;                   // 32 q-tiles of 64
    const int q0 = qt * 64;
    // 64 KB total: [0,16384) per-wave K bufs (2x2048 each);
    // [16384,24576) per-wave V buf; [24576,32768) per-wave P.
    __shared__ __align__(16) ushort smem[32768];
    const int tid = threadIdx.x;
    const int wave = tid >> 6, lane = tid & 63;
    const int lr = lane & 15, lq = lane >> 4;
    const int s8 = lane >> 3, p8 = lane & 7;  // 8 lanes per 128B row staging
    ushort* sKw = smem + wave * 4096;         // 2 bufs x 2048
    ushort* sVw = smem + 16384 + wave * 2048;
    ushort* sPw = smem + 24576 + wave * 2048;
    const ushort* Qh = Q + (size_t)bh * S_LEN * DK;
    const ushort* Kh = Km + (size_t)bh * S_LEN * DK;
    const ushort* Vh = Vt + (size_t)bh * DK * S_LEN;
    const int wsl = wave * 32;                // this wave's kpos slice base

    // ---- prologue: stage Q (64 rows x 128B at smem[0..4096), aliases wave0 K)
#pragma unroll
    for (int t = 0; t < 2; t++) {
        int row = wave * 16 + t * 8 + s8;
        int c = p8 ^ (row & 7);
        async16(&Qh[(size_t)(q0 + row) * DK + c * 8], &smem[(wave * 16 + t * 8) * 64]);
    }
    pipe_wait<0>();
    __syncthreads();
    bf16x8 qf[4][2];
#pragma unroll
    for (int nj = 0; nj < 4; nj++)
#pragma unroll
        for (int kk = 0; kk < 2; kk++)
            qf[nj][kk] = ldfrag(&smem[(nj * 16 + lr) * 64 +
                                      (((kk * 4 + lq) ^ (lr & 7)) * 8)]);
    __syncthreads();   // all waves done reading Q; wave0's K bufs may now be DMA'd

    // K slice: 32 rows x 128B, chunk swizzle c^(R&7)
    auto stageK = [&](int kt, int buf) {
        ushort* dst = sKw + buf * 2048;
#pragma unroll
        for (int t = 0; t < 4; t++) {
            int R = t * 8 + s8;
            int c = p8 ^ (R & 7);
            async16(&Kh[(size_t)(kt * 128 + wsl + R) * DK + c * 8], dst + t * 512);
        }
    };
    // V slice: 64 d-rows x 64B packed 2-per-128B-row (32 rows), swizzled
    auto stageV = [&](int kt) {
#pragma unroll
        for (int t = 0; t < 4; t++) {
            int R = t * 8 + s8;
            int c = p8 ^ (R & 7);
            int d = R * 2 + (c >> 2);
            int kc = c & 3;
            async16(&Vh[(size_t)d * S_LEN + kt * 128 + wsl + kc * 8], sVw + t * 512);
        }
    };

    stageV(0);
    stageK(0, 0);
    stageK(1, 1);
    pipe_wait<4>();    // V(0), K(0) landed; K(1) in flight

    f32x4 cacc[4][4] = {};
    float lsum[4] = {0.f, 0.f, 0.f, 0.f};
    const int r7 = (lr >> 1) & 7;             // P row-xor term

    for (int k = 0; k < 16; k++) {
        const ushort* kb = sKw + (k & 1) * 2048;

        // S^T = Kslice . Q^T : 32 kpos rows (2 mi), 64 q cols (4 nj)
        f32x4 sacc[2][4] = {};
#pragma unroll
        for (int kk = 0; kk < 2; kk++) {
            bf16x8 kf[2];
#pragma unroll
            for (int mi = 0; mi < 2; mi++) {
                int R = mi * 16 + lr;
                kf[mi] = ldfrag(&kb[R * 64 + (((kk * 4 + lq) ^ (R & 7)) * 8)]);
            }
#pragma unroll
            for (int mi = 0; mi < 2; mi++)
#pragma unroll
                for (int nj = 0; nj < 4; nj++)
                    sacc[mi][nj] = __builtin_amdgcn_mfma_f32_16x16x32_bf16(
                        kf[mi], qf[nj][kk], sacc[mi][nj], 0, 0, 0);
        }

        // P = exp2(S^T) -> private P [q 64][kpos 32] packed 2 q per 128B row
#pragma unroll
        for (int mi = 0; mi < 2; mi++)
#pragma unroll
            for (int nj = 0; nj < 4; nj++) {
                float p0 = fast_exp2(sacc[mi][nj][0]);
                float p1 = fast_exp2(sacc[mi][nj][1]);
                float p2 = fast_exp2(sacc[mi][nj][2]);
                float p3 = fast_exp2(sacc[mi][nj][3]);
                lsum[nj] += (p0 + p1) + (p2 + p3);
                uint2 w;
                w.x = packbf(p0, p1);
                w.y = packbf(p2, p3);
                int R = nj * 8 + (lr >> 1);
                int c = (lr & 1) * 8 + mi * 4 + lq;
                *(uint2*)&sPw[R * 64 + ((c ^ r7) * 4)] = w;
            }

        // ctx += P . Vslice  (K-dim 32 = one MFMA step)
        bf16x8 pf[4], vf[4];
#pragma unroll
        for (int mq = 0; mq < 4; mq++) {
            int R = mq * 8 + (lr >> 1);
            int c0 = (lr & 1) * 8 + 2 * lq;
            pf[mq] = ldfrag2(&sPw[R * 64 + ((c0 ^ r7) * 4)],
                             &sPw[R * 64 + (((c0 + 1) ^ r7) * 4)]);
        }
#pragma unroll
        for (int nd = 0; nd < 4; nd++) {
            int d = nd * 16 + lr;
            int R = nd * 8 + (lr >> 1);
            int c = (lr & 1) * 4 + lq;
            vf[nd] = ldfrag(&sVw[R * 64 + ((c ^ (R & 7)) * 8)]);
        }
#pragma unroll
        for (int mq = 0; mq < 4; mq++)
#pragma unroll
            for (int nd = 0; nd < 4; nd++)
                cacc[mq][nd] = __builtin_amdgcn_mfma_f32_16x16x32_bf16(
                    pf[mq], vf[nd], cacc[mq][nd], 0, 0, 0);

        // per-wave prefetch; FIFO: wait(4) retires V(k+1),K(k+1), leaves K(k+2)
        if (k < 14) {
            stageV(k + 1);
            stageK(k + 2, k & 1);
            pipe_wait<4>();
        } else if (k == 14) {
            stageV(15);
            pipe_wait<0>();
        }
    }

    // ---- cross-wave reduction (tree) ----
    // in-wave lsum reduce: full slice sum for q = nj*16+lr on every lane
#pragma unroll
    for (int nj = 0; nj < 4; nj++) {
        float l = lsum[nj];
        l += __shfl_xor(l, 16);
        l += __shfl_xor(l, 32);
        lsum[nj] = l;
    }
    float* red0 = (float*)smem;                    // [64 q][64 d]
    float* red1 = (float*)(smem + 8192);
    float* ls0  = (float*)(smem + 16384);          // [64]
    float* ls1  = (float*)(smem + 16512);
    __syncthreads();   // K-loop LDS fully consumed by all waves
    if (wave == 1 || wave == 3) {
        float* rd = (wave == 1) ? red0 : red1;
        float* ls = (wave == 1) ? ls0 : ls1;
#pragma unroll
        for (int mq = 0; mq < 4; mq++)
#pragma unroll
            for (int nd = 0; nd < 4; nd++)
#pragma unroll
                for (int r = 0; r < 4; r++)
                    rd[(mq * 16 + lq * 4 + r) * 64 + nd * 16 + lr] = cacc[mq][nd][r];
        if (lq == 0)
#pragma unroll
            for (int nj = 0; nj < 4; nj++) ls[nj * 16 + lr] = lsum[nj];
    }
    __syncthreads();
    if (wave == 0 || wave == 2) {
        float* rd = (wave == 0) ? red0 : red1;
        float* ls = (wave == 0) ? ls0 : ls1;
#pragma unroll
        for (int mq = 0; mq < 4; mq++)
#pragma unroll
            for (int nd = 0; nd < 4; nd++)
#pragma unroll
                for (int r = 0; r < 4; r++)
                    rd[(mq * 16 + lq * 4 + r) * 64 + nd * 16 + lr] += cacc[mq][nd][r];
        if (lq == 0)
#pragma unroll
            for (int nj = 0; nj < 4; nj++) ls[nj * 16 + lr] += lsum[nj];
    }
    __syncthreads();

    // finalize: thread t -> q = t>>2, d-group = (t&3)*16
    {
        int q = tid >> 2, dg = (tid & 3) * 16;
        float inv = __builtin_amdgcn_rcpf(ls0[q] + ls1[q]);
        float s[16];
#pragma unroll
        for (int i = 0; i < 16; i += 4) {
            f32x4 a = *(f32x4*)&red0[q * 64 + dg + i];
            f32x4 b2 = *(f32x4*)&red1[q * 64 + dg + i];
            s[i] = (a[0] + b2[0]) * inv; s[i + 1] = (a[1] + b2[1]) * inv;
            s[i + 2] = (a[2] + b2[2]) * inv; s[i + 3] = (a[3] + b2[3]) * inv;
        }
        uint4 o0, o1;
        o0.x = packbf(s[0], s[1]);  o0.y = packbf(s[2], s[3]);
        o0.z = packbf(s[4], s[5]);  o0.w = packbf(s[6], s[7]);
        o1.x = packbf(s[8], s[9]);  o1.y = packbf(s[10], s[11]);
        o1.z = packbf(s[12], s[13]); o1.w = packbf(s[14], s[15]);
        const int b = bh >> 4, h = bh & 15;
        size_t base = (size_t)(b * S_LEN + q0 + q) * D_MODEL + h * DK + dg;
        *(uint4*)&ctx[base] = o0;
        *(uint4*)&ctx[base + 8] = o1;
    }
}

// ---------------- launch ----------------

extern "C" void kernel_launch(void* const* d_in, const int* in_sizes, int n_in,
                              void* d_out, int out_size, void* d_ws, size_t ws_size,
                              hipStream_t stream) {
    const float* x  = (const float*)d_in[0];
    const float* Wq = (const float*)d_in[1];
    const float* bq = (const float*)d_in[2];
    const float* Wk = (const float*)d_in[3];
    const float* bk = (const float*)d_in[4];
    const float* Wv = (const float*)d_in[5];
    const float* bv = (const float*)d_in[6];
    const float* Wo = (const float*)d_in[7];
    const float* bo = (const float*)d_in[8];

    char* ws = (char*)d_ws;
    ushort* xb    = (ushort*)(ws);                        // 8 MB
    ushort* wqkv  = (ushort*)(ws + (8ull  << 20));        // 6 MB (B^T)
    ushort* wo_t  = (ushort*)(ws + (14ull << 20));        // 2 MB (B^T)
    ushort* qbuf  = (ushort*)(ws + (16ull << 20));        // 8 MB [32][2048][64]
    ushort* kbuf  = (ushort*)(ws + (24ull << 20));        // 8 MB [32][2048][64]
    ushort* vtb   = (ushort*)(ws + (32ull << 20));        // 8 MB [32][64][2048]
    ushort* ctx   = (ushort*)(ws + (40ull << 20));        // 8 MB [4096][1024]
    float*  biasq = (float*)(ws + (48ull << 20));         // 12 KB [3072]

    cvt_x_kernel<<<4096, 256, 0, stream>>>(x, xb);
    transpose_cvt4_kernel<<<dim3(32, 32, 4), dim3(32, 8), 0, stream>>>(
        Wq, Wk, Wv, Wo, wqkv, wqkv + 1024 * 1024, wqkv + 2 * 1024 * 1024, wo_t);
    cvt_bias_kernel<<<12, 256, 0, stream>>>(bq, bk, bv, biasq);

    gemm_kernel<0><<<768, 256, 0, stream>>>(
        xb, wqkv, biasq, qbuf, kbuf, vtb, nullptr, nullptr);
    attn_kernel<<<1024, 256, 0, stream>>>(qbuf, kbuf, vtb, ctx);
    gemm_kernel<1><<<512, 256, 0, stream>>>(
        ctx, wo_t, bo, nullptr, nullptr, nullptr, x, (float*)d_out);
}